// Round 6
// baseline (188.847 us; speedup 1.0000x reference)
//
#include <hip/hip_runtime.h>
#include <math.h>

#define HW 48
#define NPIX 2304          // 48*48
#define CF 64
#define CQ 32
#define RAD 12
#define PP 25
#define NTAP 625           // 25*25
#define KTOP 20
#define DILINT 16
#define QW 192
#define CSTRIDE 640        // corr row stride (625 padded)
#define NPB 6              // pixels per corr_band block
#define NC 30              // staged columns per row (j+dx: 0..29)
#define LROW 68            // LDS col stride in floats
#define DGS 28             // dgrid row stride

// ---- helpers ---------------------------------------------------------------

// ref_index may arrive as int32 or int64; detect via first 8 bytes.
__device__ inline int read_ref_index(const void* rip, int r) {
    const long long* p64 = (const long long*)rip;
    long long v0 = p64[0];
    if (v0 >= 0 && v0 < 1000000) return (int)p64[r];   // plausible int64 layout
    return ((const int*)rip)[r];                       // int32 layout
}

__device__ inline int get_dil(const void* refIdx, const void* curInd, int r,
                              bool* isLong) {
    int cur = ((const int*)curInd)[0];
    int gap = cur - read_ref_index(refIdx, r);
    *isLong = gap > DILINT;
    return *isLong ? min(4, gap / DILINT + 1) : 1;
}

// ---- kernel 1: layout prep -------------------------------------------------
__global__ void prep_kernel(const float* __restrict__ fr,
                            const float* __restrict__ ft,
                            const float* __restrict__ q, int nref,
                            float* __restrict__ ftT,
                            float* __restrict__ frT,
                            float* __restrict__ qrT) {
    int i = blockIdx.x * blockDim.x + threadIdx.x;
    int tft = NPIX * CF;
    int tfr = nref * NPIX * CF;
    int tqr = nref * NPIX * CQ;
    if (i < tft) {
        int p = i >> 6, c = i & 63;
        ftT[i] = ft[c * NPIX + p];
    } else if (i < tft + tfr) {
        int j = i - tft;
        int rr = j / (NPIX * CF);
        int rem = j % (NPIX * CF);
        int p = rem >> 6, c = rem & 63;
        frT[j] = fr[((size_t)rr * CF + c) * NPIX + p];
    } else if (i < tft + tfr + tqr) {
        int j = i - tft - tfr;
        int rr = j / (NPIX * CQ);
        int rem = j % (NPIX * CQ);
        int p = rem >> 5, c = rem & 31;
        int y = p / HW, x = p % HW;
        qrT[j] = q[(((size_t)rr * CQ + c) * QW + 4 * y) * QW + 4 * x];
    }
}

// ---- kernel 2a: integer-tap correlation, row-staged (round-5, unchanged) ---
__global__ __launch_bounds__(256) void corr_band(
    const float* __restrict__ ftT, const float* __restrict__ frT,
    const void* __restrict__ refIdx, const void* __restrict__ curInd,
    float* __restrict__ corr) {
    __shared__ float lrow[NC * LROW];

    int tid = threadIdx.x;
    int bx = blockIdx.x % 9;
    int y = blockIdx.x / 9;
    int r = blockIdx.y;

    bool isLong;
    int dil = get_dil(refIdx, curInd, r, &isLong);
    int nb = (dil == 3) ? 9 : 8;
    if (bx >= nb) return;

    int m = bx % dil, grp = bx / dil;
    int npr = HW / dil;

    int T = tid;
    bool active = T < NPB * PP;
    int j = active ? T / PP : 0;
    int dxi = active ? T - PP * j : 0;
    int xoff = grp * NPB + j;
    bool pvalid = active && (xoff < npr);
    int xj = m + dil * xoff;
    int pj = pvalid ? (y * HW + xj) : 0;
    int lc = j + dxi;

    float4 fq[16];
    const float4* fp = (const float4*)(ftT + (size_t)pj * CF);
#pragma unroll
    for (int i = 0; i < 16; ++i) fq[i] = fp[i];

    const float* frb = frT + (size_t)r * NPIX * CF;
    float* outb = corr + ((size_t)r * NPIX + pj) * CSTRIDE + dxi;
    int gc0 = m + dil * (grp * NPB - RAD);

    for (int dy = 0; dy < PP; ++dy) {
        int yy = y + dil * (dy - RAD);
        if (yy < 0 || yy >= HW) {
            if (pvalid) outb[dy * PP] = 0.f;
            continue;
        }
        for (int k = tid; k < NC * 16; k += 256) {
            int col = k >> 4, sub = k & 15;
            int gc = gc0 + dil * col;
            float4 v = {0.f, 0.f, 0.f, 0.f};
            if (gc >= 0 && gc < HW)
                v = *(const float4*)(frb + ((size_t)yy * HW + gc) * CF + sub * 4);
            *(float4*)(lrow + col * LROW + sub * 4) = v;
        }
        __syncthreads();
        if (pvalid) {
            const float* bp = lrow + lc * LROW;
            float s = 0.f;
#pragma unroll
            for (int i = 0; i < 16; ++i) {
                float4 b = *(const float4*)(bp + 4 * i);
                s += fq[i].x * b.x + fq[i].y * b.y + fq[i].z * b.z + fq[i].w * b.w;
            }
            outb[dy * PP] = s;
        }
        __syncthreads();
    }
}

// ---- kernel 2b: softmax/offsets + register-staged corner grid + topK -------
__global__ __launch_bounds__(256) void corr_finish(
    const float* __restrict__ ftT, const float* __restrict__ frT,
    const float* __restrict__ corr,
    const void* __restrict__ refIdx, const void* __restrict__ curInd,
    float* __restrict__ offY, float* __restrict__ offX,
    float* __restrict__ vals, int* __restrict__ topi) {
    __shared__ float dg[4][27 * DGS];

    int tid = threadIdx.x;
    int wid = tid >> 6, lane = tid & 63;
    int p = blockIdx.x * 4 + wid;
    int r = blockIdx.y;
    int y = p / HW, x = p % HW;

    bool isLong;
    int dil = get_dil(refIdx, curInd, r, &isLong);

    const float* cb = corr + ((size_t)r * NPIX + p) * CSTRIDE;
    float creg[10];
#pragma unroll
    for (int jj = 0; jj < 10; ++jj) {
        int t = lane + 64 * jj;
        creg[jj] = (t < NTAP) ? cb[t] : -INFINITY;
    }

    if (isLong) {
        // softmax over 625 taps -> expected offsets
        float M = -INFINITY;
#pragma unroll
        for (int jj = 0; jj < 10; ++jj) M = fmaxf(M, creg[jj]);
#pragma unroll
        for (int s = 32; s; s >>= 1) M = fmaxf(M, __shfl_xor(M, s, 64));
        float s0 = 0.f, sy = 0.f, sx = 0.f;
#pragma unroll
        for (int jj = 0; jj < 10; ++jj) {
            int t = lane + 64 * jj;
            if (t < NTAP) {
                float e = expf(creg[jj] - M);
                int dy = t / PP - RAD, dx = t % PP - RAD;
                s0 += e; sy += e * (float)dy; sx += e * (float)dx;
            }
        }
#pragma unroll
        for (int s = 32; s; s >>= 1) {
            s0 += __shfl_xor(s0, s, 64);
            sy += __shfl_xor(sy, s, 64);
            sx += __shfl_xor(sx, s, 64);
        }
        float oy = sy / s0 * (float)dil;
        float ox = sx / s0 * (float)dil;
        if (lane == 0) { offY[r * NPIX + p] = oy; offX[r * NPIX + p] = ox; }

        // 26x26 corner-dot grid: lane 2*lc+h owns chs [32h..32h+31] of col lc.
        // Per row: 8 coalesced float4 loads (26 cols contiguous in frT),
        // 32 FMA, 1 shfl combine. OOB row/col -> exact 0 (zero-pad semantics).
        float fy = (float)y + oy, fx = (float)x + ox;
        float fy0 = floorf(fy), fx0 = floorf(fx);
        float wy = fy - fy0, wx = fx - fx0;
        int iy0 = (int)fy0, ix0 = (int)fx0;

        int h = lane & 1;
        int lc = lane >> 1;
        float4 fh[8];
        {
            const float4* fp2 = (const float4*)(ftT + (size_t)p * CF + 32 * h);
#pragma unroll
            for (int i = 0; i < 8; ++i) fh[i] = fp2[i];
        }
        const float* frb = frT + (size_t)r * NPIX * CF;
        float* dgw = dg[wid];
        int x0c = ix0 - RAD;
        int xx = x0c + lc;
        int xs = min(max(xx, 0), HW - 1);        // clamp for addr locality
        bool vcol = (xx >= 0 && xx < HW);
        for (int a = 0; a < 26; ++a) {
            int yy = iy0 - RAD + a;
            float s = 0.f;
            if (yy >= 0 && yy < HW) {            // wave-uniform branch
                const float4* cp =
                    (const float4*)(frb + ((size_t)yy * HW + xs) * CF + 32 * h);
                float t0 = 0.f;
#pragma unroll
                for (int i = 0; i < 8; ++i) {
                    float4 b = cp[i];
                    t0 += fh[i].x * b.x + fh[i].y * b.y + fh[i].z * b.z + fh[i].w * b.w;
                }
                s = vcol ? t0 : 0.f;
            }
            s += __shfl_xor(s, 1, 64);
            if (h == 0 && lc < 26) dgw[a * DGS + lc] = s;
        }
        __builtin_amdgcn_wave_barrier();
        asm volatile("s_waitcnt lgkmcnt(0)" ::: "memory");
        __builtin_amdgcn_sched_barrier(0);

        float w00 = (1.f - wy) * (1.f - wx), w01 = (1.f - wy) * wx;
        float w10 = wy * (1.f - wx), w11 = wy * wx;
#pragma unroll
        for (int jj = 0; jj < 10; ++jj) {
            int t = lane + 64 * jj;
            if (t < NTAP) {
                int a = t / PP, bcol = t % PP;
                creg[jj] = w00 * dgw[a * DGS + bcol] + w01 * dgw[a * DGS + bcol + 1] +
                           w10 * dgw[(a + 1) * DGS + bcol] + w11 * dgw[(a + 1) * DGS + bcol + 1];
            }
        }
    }

    // top-K: 20 rounds of register argmax + shuffle butterfly; tie -> lowest t
    float* vout = vals + (size_t)r * KTOP * NPIX + p;
    int* iout = topi + (size_t)r * KTOP * NPIX + p;
    for (int k = 0; k < KTOP; ++k) {
        float bv = creg[0]; int bt = lane;
#pragma unroll
        for (int jj = 1; jj < 10; ++jj) {
            int t = lane + 64 * jj;
            if (creg[jj] > bv) { bv = creg[jj]; bt = t; }
        }
#pragma unroll
        for (int s = 32; s; s >>= 1) {
            float ov = __shfl_xor(bv, s, 64);
            int ot = __shfl_xor(bt, s, 64);
            if (ov > bv || (ov == bv && ot < bt)) { bv = ov; bt = ot; }
        }
        if (lane == 0) { vout[(size_t)k * NPIX] = bv; iout[(size_t)k * NPIX] = bt; }
        if ((bt & 63) == lane) {
            int jj2 = bt >> 6;
#pragma unroll
            for (int jj = 0; jj < 10; ++jj)
                if (jj == jj2) creg[jj] = -INFINITY;
        }
    }
}

// ---- kernel 3: softmax over 60 vals + gather colors + blend ---------------
__global__ __launch_bounds__(256) void finalize_kernel(
    const float* __restrict__ qrT, const float* __restrict__ vals,
    const int* __restrict__ topi, const float* __restrict__ offY,
    const float* __restrict__ offX, const void* __restrict__ refIdx,
    const void* __restrict__ curInd, int nref, float* __restrict__ out) {
    int tid = threadIdx.x;
    int p = blockIdx.x * 8 + (tid >> 5);
    int c = tid & 31;
    if (p >= NPIX) return;
    int y = p / HW, x = p % HW;
    int nk = nref * KTOP;

    float m = -INFINITY;
    for (int k = 0; k < nk; ++k) m = fmaxf(m, vals[(size_t)k * NPIX + p]);

    float ssum = 0.f, acc = 0.f;
    for (int rr = 0; rr < nref; ++rr) {
        bool isLong;
        get_dil(refIdx, curInd, rr, &isLong);
        float oy = 0.f, ox = 0.f;
        if (isLong) { oy = offY[rr * NPIX + p]; ox = offX[rr * NPIX + p]; }
        const float* qb = qrT + (size_t)rr * NPIX * CQ;
        for (int k = 0; k < KTOP; ++k) {
            int kk = rr * KTOP + k;
            float e = expf(vals[(size_t)kk * NPIX + p] - m);
            ssum += e;
            int id = topi[(size_t)kk * NPIX + p];
            int dr = id / PP - RAD, dc = id % PP - RAD;
            float img = 0.f;
            if (isLong) {
                float py = (float)y + oy + (float)dr;
                float px = (float)x + ox + (float)dc;
                float fy0 = floorf(py), fx0 = floorf(px);
                int y0 = (int)fy0, x0 = (int)fx0;
                float wy = py - fy0, wx = px - fx0;
                float w00 = (1.f - wy) * (1.f - wx), w01 = (1.f - wy) * wx;
                float w10 = wy * (1.f - wx), w11 = wy * wx;
                if (y0 >= 0 && y0 < HW && x0 >= 0 && x0 < HW)
                    img += w00 * qb[(y0 * HW + x0) * CQ + c];
                if (y0 >= 0 && y0 < HW && x0 + 1 >= 0 && x0 + 1 < HW)
                    img += w01 * qb[(y0 * HW + x0 + 1) * CQ + c];
                if (y0 + 1 >= 0 && y0 + 1 < HW && x0 >= 0 && x0 < HW)
                    img += w10 * qb[((y0 + 1) * HW + x0) * CQ + c];
                if (y0 + 1 >= 0 && y0 + 1 < HW && x0 + 1 >= 0 && x0 + 1 < HW)
                    img += w11 * qb[((y0 + 1) * HW + x0 + 1) * CQ + c];
            } else {
                int yy = y + dr, xx = x + dc;
                if (yy >= 0 && yy < HW && xx >= 0 && xx < HW)
                    img = qb[(yy * HW + xx) * CQ + c];
            }
            acc += e * img;
        }
    }
    out[(size_t)c * NPIX + p] = acc / ssum;
}

// ---- launcher --------------------------------------------------------------
extern "C" void kernel_launch(void* const* d_in, const int* in_sizes, int n_in,
                              void* d_out, int out_size, void* d_ws, size_t ws_size,
                              hipStream_t stream) {
    const float* fr = (const float*)d_in[0];   // (nref,1,64,48,48)
    const float* ft = (const float*)d_in[1];   // (1,64,48,48)
    const float* q  = (const float*)d_in[2];   // (nref,1,32,192,192)
    const void* refIdx = d_in[3];
    const void* curInd = d_in[4];
    int nref = in_sizes[0] / (CF * NPIX);

    float* ws  = (float*)d_ws;
    float* ftT = ws;
    float* frT = ftT + (size_t)NPIX * CF;
    float* qrT = frT + (size_t)nref * NPIX * CF;
    float* oY  = qrT + (size_t)nref * NPIX * CQ;
    float* oX  = oY + (size_t)nref * NPIX;
    float* vls = oX + (size_t)nref * NPIX;
    int* topi  = (int*)(vls + (size_t)nref * KTOP * NPIX);
    float* corr = (float*)(topi + (size_t)nref * KTOP * NPIX);

    int total = NPIX * CF + nref * NPIX * CF + nref * NPIX * CQ;
    prep_kernel<<<(total + 255) / 256, 256, 0, stream>>>(fr, ft, q, nref, ftT, frT, qrT);
    corr_band<<<dim3(HW * 9, nref), 256, 0, stream>>>(ftT, frT, refIdx, curInd, corr);
    corr_finish<<<dim3(NPIX / 4, nref), 256, 0, stream>>>(ftT, frT, corr, refIdx, curInd,
                                                          oY, oX, vls, topi);
    finalize_kernel<<<((NPIX * CQ) + 255) / 256, 256, 0, stream>>>(
        qrT, vls, topi, oY, oX, refIdx, curInd, nref, (float*)d_out);
}

// Round 7
// 167.758 us; speedup vs baseline: 1.1257x; 1.1257x over previous
//
#include <hip/hip_runtime.h>
#include <math.h>

#define HW 48
#define NPIX 2304          // 48*48
#define CF 64
#define CQ 32
#define RAD 12
#define PP 25
#define NTAP 625           // 25*25
#define KTOP 20
#define DILINT 16
#define QW 192
#define CSTRIDE 640        // corr row stride (625 padded)
#define NPB 6              // pixels per corr_band block
#define NC 30              // staged columns per row (j+dx: 0..29)
#define LROW 68            // LDS col stride in floats
#define DGS 28             // dgrid row stride

// ---- helpers ---------------------------------------------------------------

// ref_index may arrive as int32 or int64; detect via first 8 bytes.
__device__ inline int read_ref_index(const void* rip, int r) {
    const long long* p64 = (const long long*)rip;
    long long v0 = p64[0];
    if (v0 >= 0 && v0 < 1000000) return (int)p64[r];   // plausible int64 layout
    return ((const int*)rip)[r];                       // int32 layout
}

__device__ inline int get_dil(const void* refIdx, const void* curInd, int r,
                              bool* isLong) {
    int cur = ((const int*)curInd)[0];
    int gap = cur - read_ref_index(refIdx, r);
    *isLong = gap > DILINT;
    return *isLong ? min(4, gap / DILINT + 1) : 1;
}

// ---- kernel 1: layout prep -------------------------------------------------
__global__ void prep_kernel(const float* __restrict__ fr,
                            const float* __restrict__ ft,
                            const float* __restrict__ q, int nref,
                            float* __restrict__ ftT,
                            float* __restrict__ frT,
                            float* __restrict__ qrT) {
    int i = blockIdx.x * blockDim.x + threadIdx.x;
    int tft = NPIX * CF;
    int tfr = nref * NPIX * CF;
    int tqr = nref * NPIX * CQ;
    if (i < tft) {
        int p = i >> 6, c = i & 63;
        ftT[i] = ft[c * NPIX + p];
    } else if (i < tft + tfr) {
        int j = i - tft;
        int rr = j / (NPIX * CF);
        int rem = j % (NPIX * CF);
        int p = rem >> 6, c = rem & 63;
        frT[j] = fr[((size_t)rr * CF + c) * NPIX + p];
    } else if (i < tft + tfr + tqr) {
        int j = i - tft - tfr;
        int rr = j / (NPIX * CQ);
        int rem = j % (NPIX * CQ);
        int p = rem >> 5, c = rem & 31;
        int y = p / HW, x = p % HW;
        qrT[j] = q[(((size_t)rr * CQ + c) * QW + 4 * y) * QW + 4 * x];
    }
}

// ---- kernel 2a: integer-tap correlation, row-staged (round-5, unchanged) ---
__global__ __launch_bounds__(256) void corr_band(
    const float* __restrict__ ftT, const float* __restrict__ frT,
    const void* __restrict__ refIdx, const void* __restrict__ curInd,
    float* __restrict__ corr) {
    __shared__ float lrow[NC * LROW];

    int tid = threadIdx.x;
    int bx = blockIdx.x % 9;
    int y = blockIdx.x / 9;
    int r = blockIdx.y;

    bool isLong;
    int dil = get_dil(refIdx, curInd, r, &isLong);
    int nb = (dil == 3) ? 9 : 8;
    if (bx >= nb) return;

    int m = bx % dil, grp = bx / dil;
    int npr = HW / dil;

    int T = tid;
    bool active = T < NPB * PP;
    int j = active ? T / PP : 0;
    int dxi = active ? T - PP * j : 0;
    int xoff = grp * NPB + j;
    bool pvalid = active && (xoff < npr);
    int xj = m + dil * xoff;
    int pj = pvalid ? (y * HW + xj) : 0;
    int lc = j + dxi;

    float4 fq[16];
    const float4* fp = (const float4*)(ftT + (size_t)pj * CF);
#pragma unroll
    for (int i = 0; i < 16; ++i) fq[i] = fp[i];

    const float* frb = frT + (size_t)r * NPIX * CF;
    float* outb = corr + ((size_t)r * NPIX + pj) * CSTRIDE + dxi;
    int gc0 = m + dil * (grp * NPB - RAD);

    for (int dy = 0; dy < PP; ++dy) {
        int yy = y + dil * (dy - RAD);
        if (yy < 0 || yy >= HW) {
            if (pvalid) outb[dy * PP] = 0.f;
            continue;
        }
        for (int k = tid; k < NC * 16; k += 256) {
            int col = k >> 4, sub = k & 15;
            int gc = gc0 + dil * col;
            float4 v = {0.f, 0.f, 0.f, 0.f};
            if (gc >= 0 && gc < HW)
                v = *(const float4*)(frb + ((size_t)yy * HW + gc) * CF + sub * 4);
            *(float4*)(lrow + col * LROW + sub * 4) = v;
        }
        __syncthreads();
        if (pvalid) {
            const float* bp = lrow + lc * LROW;
            float s = 0.f;
#pragma unroll
            for (int i = 0; i < 16; ++i) {
                float4 b = *(const float4*)(bp + 4 * i);
                s += fq[i].x * b.x + fq[i].y * b.y + fq[i].z * b.z + fq[i].w * b.w;
            }
            outb[dy * PP] = s;
        }
        __syncthreads();
    }
}

// ---- kernel 2b: fused per-pixel wave: all refs -> softmax/offsets ->
//      corner grid -> topK -> 60-way softmax + color gather + blend ---------
__global__ __launch_bounds__(64) void corr_fuse(
    const float* __restrict__ ftT, const float* __restrict__ frT,
    const float* __restrict__ qrT, const float* __restrict__ corr,
    const void* __restrict__ refIdx, const void* __restrict__ curInd,
    int nref, float* __restrict__ out) {
    __shared__ float dgw[27 * DGS];
    __shared__ float valsL[96];
    __shared__ int   topiL[96];
    __shared__ float offL[8][2];

    int lane = threadIdx.x;
    int g = lane >> 4, cs = lane & 15;
    int p = blockIdx.x;
    int y = p / HW, x = p % HW;

    for (int r = 0; r < nref; ++r) {
        bool isLong;
        int dil = get_dil(refIdx, curInd, r, &isLong);
        const float* cb = corr + ((size_t)r * NPIX + p) * CSTRIDE;
        float creg[10];
#pragma unroll
        for (int jj = 0; jj < 10; ++jj) {
            int t = lane + 64 * jj;
            creg[jj] = (t < NTAP) ? cb[t] : -INFINITY;
        }

        if (isLong) {
            // softmax over 625 taps -> expected offsets
            float M = -INFINITY;
#pragma unroll
            for (int jj = 0; jj < 10; ++jj) M = fmaxf(M, creg[jj]);
#pragma unroll
            for (int s = 32; s; s >>= 1) M = fmaxf(M, __shfl_xor(M, s, 64));
            float s0 = 0.f, sy = 0.f, sx = 0.f;
#pragma unroll
            for (int jj = 0; jj < 10; ++jj) {
                int t = lane + 64 * jj;
                if (t < NTAP) {
                    float e = expf(creg[jj] - M);
                    int dy = t / PP - RAD, dx = t % PP - RAD;
                    s0 += e; sy += e * (float)dy; sx += e * (float)dx;
                }
            }
#pragma unroll
            for (int s = 32; s; s >>= 1) {
                s0 += __shfl_xor(s0, s, 64);
                sy += __shfl_xor(sy, s, 64);
                sx += __shfl_xor(sx, s, 64);
            }
            float oy = sy / s0 * (float)dil;
            float ox = sx / s0 * (float)dil;
            if (lane == 0) { offL[r][0] = oy; offL[r][1] = ox; }

            // 26x26 corner-dot grid, coop-16 dots, 1KB-contiguous loads,
            // no div/mod (26 rows x 7 unrolled col-rounds), clamp+mask OOB.
            float fy = (float)y + oy, fx = (float)x + ox;
            float fy0 = floorf(fy), fx0 = floorf(fx);
            float wy = fy - fy0, wx = fx - fx0;
            int iy0 = (int)fy0, ix0 = (int)fx0;

            float4 fqc = ((const float4*)(ftT + (size_t)p * CF))[cs];
            const float* frb = frT + (size_t)r * NPIX * CF;
            int colbase = ix0 - RAD;
            for (int a = 0; a < 26; ++a) {
                int yy = iy0 - RAD + a;
                bool yok = (yy >= 0 && yy < HW);
                const float* rowp = frb + (size_t)(yok ? yy : 0) * (HW * CF);
#pragma unroll
                for (int i = 0; i < 7; ++i) {
                    int lc2 = 4 * i + g;
                    int xx2 = colbase + lc2;
                    int xs = min(max(xx2, 0), HW - 1);
                    float s = 0.f;
                    if (yok) {
                        float4 b = *(const float4*)(rowp + xs * CF + 4 * cs);
                        s = fqc.x * b.x + fqc.y * b.y + fqc.z * b.z + fqc.w * b.w;
                        s = (xx2 >= 0 && xx2 < HW) ? s : 0.f;
                    }
                    s += __shfl_xor(s, 1, 64);
                    s += __shfl_xor(s, 2, 64);
                    s += __shfl_xor(s, 4, 64);
                    s += __shfl_xor(s, 8, 64);
                    if (cs == 0 && lc2 < 26) dgw[a * DGS + lc2] = s;
                }
            }
            __builtin_amdgcn_wave_barrier();
            asm volatile("s_waitcnt lgkmcnt(0)" ::: "memory");
            __builtin_amdgcn_sched_barrier(0);

            float w00 = (1.f - wy) * (1.f - wx), w01 = (1.f - wy) * wx;
            float w10 = wy * (1.f - wx), w11 = wy * wx;
#pragma unroll
            for (int jj = 0; jj < 10; ++jj) {
                int t = lane + 64 * jj;
                if (t < NTAP) {
                    int a = t / PP, bcol = t % PP;
                    creg[jj] = w00 * dgw[a * DGS + bcol] + w01 * dgw[a * DGS + bcol + 1] +
                               w10 * dgw[(a + 1) * DGS + bcol] + w11 * dgw[(a + 1) * DGS + bcol + 1];
                }
            }
        }

        // top-K: tie -> lowest tap index (lax.top_k semantics); results to LDS
        for (int k = 0; k < KTOP; ++k) {
            float bv = creg[0]; int bt = lane;
#pragma unroll
            for (int jj = 1; jj < 10; ++jj) {
                int t = lane + 64 * jj;
                if (creg[jj] > bv) { bv = creg[jj]; bt = t; }
            }
#pragma unroll
            for (int s = 32; s; s >>= 1) {
                float ov = __shfl_xor(bv, s, 64);
                int ot = __shfl_xor(bt, s, 64);
                if (ov > bv || (ov == bv && ot < bt)) { bv = ov; bt = ot; }
            }
            if (lane == 0) { valsL[r * KTOP + k] = bv; topiL[r * KTOP + k] = bt; }
            if ((bt & 63) == lane) {
                int jj2 = bt >> 6;
#pragma unroll
                for (int jj = 0; jj < 10; ++jj)
                    if (jj == jj2) creg[jj] = -INFINITY;
            }
        }
    }

    __builtin_amdgcn_wave_barrier();
    asm volatile("s_waitcnt lgkmcnt(0)" ::: "memory");
    __builtin_amdgcn_sched_barrier(0);

    // fused finalize: lane = (channel c, tap-half h); 10 taps/ref each half
    int c = lane & 31, h = lane >> 5;
    int nk = nref * KTOP;
    float m = -INFINITY;
    for (int k = 0; k < nk; ++k) m = fmaxf(m, valsL[k]);

    float ssum = 0.f, acc = 0.f;
    for (int r = 0; r < nref; ++r) {
        bool isLong;
        get_dil(refIdx, curInd, r, &isLong);
        float oy = 0.f, ox = 0.f;
        if (isLong) { oy = offL[r][0]; ox = offL[r][1]; }
        const float* qb = qrT + (size_t)r * NPIX * CQ;
        for (int k2 = 0; k2 < KTOP / 2; ++k2) {
            int k = r * KTOP + h * (KTOP / 2) + k2;
            float e = expf(valsL[k] - m);
            ssum += e;
            int id = topiL[k];
            int dr = id / PP - RAD, dc = id % PP - RAD;
            float img = 0.f;
            if (isLong) {
                float py = (float)y + oy + (float)dr;
                float px = (float)x + ox + (float)dc;
                float fy0 = floorf(py), fx0 = floorf(px);
                int y0 = (int)fy0, x0 = (int)fx0;
                float wy = py - fy0, wx = px - fx0;
                float w00 = (1.f - wy) * (1.f - wx), w01 = (1.f - wy) * wx;
                float w10 = wy * (1.f - wx), w11 = wy * wx;
                if (y0 >= 0 && y0 < HW && x0 >= 0 && x0 < HW)
                    img += w00 * qb[(y0 * HW + x0) * CQ + c];
                if (y0 >= 0 && y0 < HW && x0 + 1 >= 0 && x0 + 1 < HW)
                    img += w01 * qb[(y0 * HW + x0 + 1) * CQ + c];
                if (y0 + 1 >= 0 && y0 + 1 < HW && x0 >= 0 && x0 < HW)
                    img += w10 * qb[((y0 + 1) * HW + x0) * CQ + c];
                if (y0 + 1 >= 0 && y0 + 1 < HW && x0 + 1 >= 0 && x0 + 1 < HW)
                    img += w11 * qb[((y0 + 1) * HW + x0 + 1) * CQ + c];
            } else {
                int yy = y + dr, xx = x + dc;
                if (yy >= 0 && yy < HW && xx >= 0 && xx < HW)
                    img = qb[(yy * HW + xx) * CQ + c];
            }
            acc += e * img;
        }
    }
    ssum += __shfl_xor(ssum, 32, 64);
    acc  += __shfl_xor(acc, 32, 64);
    if (h == 0) out[(size_t)c * NPIX + p] = acc / ssum;
}

// ---- launcher --------------------------------------------------------------
extern "C" void kernel_launch(void* const* d_in, const int* in_sizes, int n_in,
                              void* d_out, int out_size, void* d_ws, size_t ws_size,
                              hipStream_t stream) {
    const float* fr = (const float*)d_in[0];   // (nref,1,64,48,48)
    const float* ft = (const float*)d_in[1];   // (1,64,48,48)
    const float* q  = (const float*)d_in[2];   // (nref,1,32,192,192)
    const void* refIdx = d_in[3];
    const void* curInd = d_in[4];
    int nref = in_sizes[0] / (CF * NPIX);

    float* ws  = (float*)d_ws;
    float* ftT = ws;
    float* frT = ftT + (size_t)NPIX * CF;
    float* qrT = frT + (size_t)nref * NPIX * CF;
    float* corr = qrT + (size_t)nref * NPIX * CQ;

    int total = NPIX * CF + nref * NPIX * CF + nref * NPIX * CQ;
    prep_kernel<<<(total + 255) / 256, 256, 0, stream>>>(fr, ft, q, nref, ftT, frT, qrT);
    corr_band<<<dim3(HW * 9, nref), 256, 0, stream>>>(ftT, frT, refIdx, curInd, corr);
    corr_fuse<<<dim3(NPIX), 64, 0, stream>>>(ftT, frT, qrT, corr, refIdx, curInd,
                                             nref, (float*)d_out);
}

// Round 8
// 139.681 us; speedup vs baseline: 1.3520x; 1.2010x over previous
//
#include <hip/hip_runtime.h>
#include <math.h>

#define HW 48
#define NPIX 2304          // 48*48
#define CF 64
#define CQ 32
#define RAD 12
#define PP 25
#define NTAP 625           // 25*25
#define KTOP 20
#define DILINT 16
#define QW 192
#define CSTRIDE 640        // corr row stride (625 padded)
#define NPB 6              // pixels per corr_band block
#define NC 30              // staged columns per row (j+dx: 0..29)
#define LROW 68            // LDS col stride in floats
#define DGS 28             // dgrid row stride

// ---- helpers ---------------------------------------------------------------

// ref_index may arrive as int32 or int64; detect via first 8 bytes.
__device__ inline int read_ref_index(const void* rip, int r) {
    const long long* p64 = (const long long*)rip;
    long long v0 = p64[0];
    if (v0 >= 0 && v0 < 1000000) return (int)p64[r];   // plausible int64 layout
    return ((const int*)rip)[r];                       // int32 layout
}

__device__ inline int get_dil(const void* refIdx, const void* curInd, int r,
                              bool* isLong) {
    int cur = ((const int*)curInd)[0];
    int gap = cur - read_ref_index(refIdx, r);
    *isLong = gap > DILINT;
    return *isLong ? min(4, gap / DILINT + 1) : 1;
}

// ---- kernel 1: layout prep -------------------------------------------------
__global__ void prep_kernel(const float* __restrict__ fr,
                            const float* __restrict__ ft,
                            const float* __restrict__ q, int nref,
                            float* __restrict__ ftT,
                            float* __restrict__ frT,
                            float* __restrict__ qrT) {
    int i = blockIdx.x * blockDim.x + threadIdx.x;
    int tft = NPIX * CF;
    int tfr = nref * NPIX * CF;
    int tqr = nref * NPIX * CQ;
    if (i < tft) {
        int p = i >> 6, c = i & 63;
        ftT[i] = ft[c * NPIX + p];
    } else if (i < tft + tfr) {
        int j = i - tft;
        int rr = j / (NPIX * CF);
        int rem = j % (NPIX * CF);
        int p = rem >> 6, c = rem & 63;
        frT[j] = fr[((size_t)rr * CF + c) * NPIX + p];
    } else if (i < tft + tfr + tqr) {
        int j = i - tft - tfr;
        int rr = j / (NPIX * CQ);
        int rem = j % (NPIX * CQ);
        int p = rem >> 5, c = rem & 31;
        int y = p / HW, x = p % HW;
        qrT[j] = q[(((size_t)rr * CQ + c) * QW + 4 * y) * QW + 4 * x];
    }
}

// ---- kernel 2a: integer-tap correlation, row-staged (unchanged) ------------
__global__ __launch_bounds__(256) void corr_band(
    const float* __restrict__ ftT, const float* __restrict__ frT,
    const void* __restrict__ refIdx, const void* __restrict__ curInd,
    float* __restrict__ corr) {
    __shared__ float lrow[NC * LROW];

    int tid = threadIdx.x;
    int bx = blockIdx.x % 9;
    int y = blockIdx.x / 9;
    int r = blockIdx.y;

    bool isLong;
    int dil = get_dil(refIdx, curInd, r, &isLong);
    int nb = (dil == 3) ? 9 : 8;
    if (bx >= nb) return;

    int m = bx % dil, grp = bx / dil;
    int npr = HW / dil;

    int T = tid;
    bool active = T < NPB * PP;
    int j = active ? T / PP : 0;
    int dxi = active ? T - PP * j : 0;
    int xoff = grp * NPB + j;
    bool pvalid = active && (xoff < npr);
    int xj = m + dil * xoff;
    int pj = pvalid ? (y * HW + xj) : 0;
    int lc = j + dxi;

    float4 fq[16];
    const float4* fp = (const float4*)(ftT + (size_t)pj * CF);
#pragma unroll
    for (int i = 0; i < 16; ++i) fq[i] = fp[i];

    const float* frb = frT + (size_t)r * NPIX * CF;
    float* outb = corr + ((size_t)r * NPIX + pj) * CSTRIDE + dxi;
    int gc0 = m + dil * (grp * NPB - RAD);

    for (int dy = 0; dy < PP; ++dy) {
        int yy = y + dil * (dy - RAD);
        if (yy < 0 || yy >= HW) {
            if (pvalid) outb[dy * PP] = 0.f;
            continue;
        }
        for (int k = tid; k < NC * 16; k += 256) {
            int col = k >> 4, sub = k & 15;
            int gc = gc0 + dil * col;
            float4 v = {0.f, 0.f, 0.f, 0.f};
            if (gc >= 0 && gc < HW)
                v = *(const float4*)(frb + ((size_t)yy * HW + gc) * CF + sub * 4);
            *(float4*)(lrow + col * LROW + sub * 4) = v;
        }
        __syncthreads();
        if (pvalid) {
            const float* bp = lrow + lc * LROW;
            float s = 0.f;
#pragma unroll
            for (int i = 0; i < 16; ++i) {
                float4 b = *(const float4*)(bp + 4 * i);
                s += fq[i].x * b.x + fq[i].y * b.y + fq[i].z * b.z + fq[i].w * b.w;
            }
            outb[dy * PP] = s;
        }
        __syncthreads();
    }
}

// ---- kernel 2b: fused per-pixel block, one wave per ref --------------------
// Wave w owns ref w: softmax/offsets + corner grid (long) + topK -> LDS.
// Then per-wave partial finalize (own ref's 20 taps), wave 0 combines.
__global__ __launch_bounds__(192) void corr_fuse(
    const float* __restrict__ ftT, const float* __restrict__ frT,
    const float* __restrict__ qrT, const float* __restrict__ corr,
    const void* __restrict__ refIdx, const void* __restrict__ curInd,
    int nref, float* __restrict__ out) {
    __shared__ float dgw_s[3][27 * DGS];
    __shared__ float valsL[96];
    __shared__ int   topiL[96];
    __shared__ float accL[3][64];
    __shared__ float ssmL[3][64];

    int tid = threadIdx.x;
    int wid = tid >> 6, lane = tid & 63;
    int g = lane >> 4, cs = lane & 15;
    int p = blockIdx.x;
    int y = p / HW, x = p % HW;
    int r = wid;                      // one wave per ref (block = 64*nref)

    bool isLong;
    int dil = get_dil(refIdx, curInd, r, &isLong);
    float oy = 0.f, ox = 0.f;

    const float* cb = corr + ((size_t)r * NPIX + p) * CSTRIDE;
    float creg[10];
#pragma unroll
    for (int jj = 0; jj < 10; ++jj) {
        int t = lane + 64 * jj;
        creg[jj] = (t < NTAP) ? cb[t] : -INFINITY;
    }

    if (isLong) {
        // softmax over 625 taps -> expected offsets
        float M = -INFINITY;
#pragma unroll
        for (int jj = 0; jj < 10; ++jj) M = fmaxf(M, creg[jj]);
#pragma unroll
        for (int s = 32; s; s >>= 1) M = fmaxf(M, __shfl_xor(M, s, 64));
        float s0 = 0.f, sy = 0.f, sx = 0.f;
#pragma unroll
        for (int jj = 0; jj < 10; ++jj) {
            int t = lane + 64 * jj;
            if (t < NTAP) {
                float e = expf(creg[jj] - M);
                int dy = t / PP - RAD, dx = t % PP - RAD;
                s0 += e; sy += e * (float)dy; sx += e * (float)dx;
            }
        }
#pragma unroll
        for (int s = 32; s; s >>= 1) {
            s0 += __shfl_xor(s0, s, 64);
            sy += __shfl_xor(sy, s, 64);
            sx += __shfl_xor(sx, s, 64);
        }
        oy = sy / s0 * (float)dil;
        ox = sx / s0 * (float)dil;

        // 26x26 corner-dot grid, coop-16 dots (1KB contiguous loads)
        float fy = (float)y + oy, fx = (float)x + ox;
        float fy0 = floorf(fy), fx0 = floorf(fx);
        float wy = fy - fy0, wx = fx - fx0;
        int iy0 = (int)fy0, ix0 = (int)fx0;

        float4 fqc = ((const float4*)(ftT + (size_t)p * CF))[cs];
        const float* frb = frT + (size_t)r * NPIX * CF;
        float* dgw = dgw_s[wid];
        int colbase = ix0 - RAD;
        for (int a = 0; a < 26; ++a) {
            int yy = iy0 - RAD + a;
            bool yok = (yy >= 0 && yy < HW);
            const float* rowp = frb + (size_t)(yok ? yy : 0) * (HW * CF);
#pragma unroll
            for (int i = 0; i < 7; ++i) {
                int lc2 = 4 * i + g;
                int xx2 = colbase + lc2;
                int xs = min(max(xx2, 0), HW - 1);
                float s = 0.f;
                if (yok) {
                    float4 b = *(const float4*)(rowp + xs * CF + 4 * cs);
                    s = fqc.x * b.x + fqc.y * b.y + fqc.z * b.z + fqc.w * b.w;
                    s = (xx2 >= 0 && xx2 < HW) ? s : 0.f;
                }
                s += __shfl_xor(s, 1, 64);
                s += __shfl_xor(s, 2, 64);
                s += __shfl_xor(s, 4, 64);
                s += __shfl_xor(s, 8, 64);
                if (cs == 0 && lc2 < 26) dgw[a * DGS + lc2] = s;
            }
        }
        __builtin_amdgcn_wave_barrier();
        asm volatile("s_waitcnt lgkmcnt(0)" ::: "memory");
        __builtin_amdgcn_sched_barrier(0);

        float w00 = (1.f - wy) * (1.f - wx), w01 = (1.f - wy) * wx;
        float w10 = wy * (1.f - wx), w11 = wy * wx;
#pragma unroll
        for (int jj = 0; jj < 10; ++jj) {
            int t = lane + 64 * jj;
            if (t < NTAP) {
                int a = t / PP, bcol = t % PP;
                creg[jj] = w00 * dgw[a * DGS + bcol] + w01 * dgw[a * DGS + bcol + 1] +
                           w10 * dgw[(a + 1) * DGS + bcol] + w11 * dgw[(a + 1) * DGS + bcol + 1];
            }
        }
    }

    // top-K for this wave's ref: tie -> lowest tap index
    for (int k = 0; k < KTOP; ++k) {
        float bv = creg[0]; int bt = lane;
#pragma unroll
        for (int jj = 1; jj < 10; ++jj) {
            int t = lane + 64 * jj;
            if (creg[jj] > bv) { bv = creg[jj]; bt = t; }
        }
#pragma unroll
        for (int s = 32; s; s >>= 1) {
            float ov = __shfl_xor(bv, s, 64);
            int ot = __shfl_xor(bt, s, 64);
            if (ov > bv || (ov == bv && ot < bt)) { bv = ov; bt = ot; }
        }
        if (lane == 0) { valsL[r * KTOP + k] = bv; topiL[r * KTOP + k] = bt; }
        if ((bt & 63) == lane) {
            int jj2 = bt >> 6;
#pragma unroll
            for (int jj = 0; jj < 10; ++jj)
                if (jj == jj2) creg[jj] = -INFINITY;
        }
    }
    __syncthreads();

    // per-wave partial finalize: own ref's 20 taps; lane = (channel, half)
    int c = lane & 31, h = lane >> 5;
    int nk = nref * KTOP;
    float m = -INFINITY;
    for (int k = 0; k < nk; ++k) m = fmaxf(m, valsL[k]);

    float ssum = 0.f, acc = 0.f;
    const float* qb = qrT + (size_t)r * NPIX * CQ;
    for (int k2 = 0; k2 < KTOP / 2; ++k2) {
        int k = r * KTOP + h * (KTOP / 2) + k2;
        float e = expf(valsL[k] - m);
        ssum += e;
        int id = topiL[k];
        int dr = id / PP - RAD, dc = id % PP - RAD;
        float img = 0.f;
        if (isLong) {
            float py = (float)y + oy + (float)dr;
            float px = (float)x + ox + (float)dc;
            float fy0 = floorf(py), fx0 = floorf(px);
            int y0 = (int)fy0, x0 = (int)fx0;
            float wy = py - fy0, wx = px - fx0;
            float w00 = (1.f - wy) * (1.f - wx), w01 = (1.f - wy) * wx;
            float w10 = wy * (1.f - wx), w11 = wy * wx;
            if (y0 >= 0 && y0 < HW && x0 >= 0 && x0 < HW)
                img += w00 * qb[(y0 * HW + x0) * CQ + c];
            if (y0 >= 0 && y0 < HW && x0 + 1 >= 0 && x0 + 1 < HW)
                img += w01 * qb[(y0 * HW + x0 + 1) * CQ + c];
            if (y0 + 1 >= 0 && y0 + 1 < HW && x0 >= 0 && x0 < HW)
                img += w10 * qb[((y0 + 1) * HW + x0) * CQ + c];
            if (y0 + 1 >= 0 && y0 + 1 < HW && x0 + 1 >= 0 && x0 + 1 < HW)
                img += w11 * qb[((y0 + 1) * HW + x0 + 1) * CQ + c];
        } else {
            int yy = y + dr, xx = x + dc;
            if (yy >= 0 && yy < HW && xx >= 0 && xx < HW)
                img = qb[(yy * HW + xx) * CQ + c];
        }
        acc += e * img;
    }
    accL[wid][lane] = acc;
    ssmL[wid][lane] = ssum;
    __syncthreads();

    if (wid == 0) {
        float ta = 0.f, ts = 0.f;
        for (int w = 0; w < nref; ++w) { ta += accL[w][lane]; ts += ssmL[w][lane]; }
        ta += __shfl_xor(ta, 32, 64);
        ts += __shfl_xor(ts, 32, 64);
        if (h == 0) out[(size_t)c * NPIX + p] = ta / ts;
    }
}

// ---- launcher --------------------------------------------------------------
extern "C" void kernel_launch(void* const* d_in, const int* in_sizes, int n_in,
                              void* d_out, int out_size, void* d_ws, size_t ws_size,
                              hipStream_t stream) {
    const float* fr = (const float*)d_in[0];   // (nref,1,64,48,48)
    const float* ft = (const float*)d_in[1];   // (1,64,48,48)
    const float* q  = (const float*)d_in[2];   // (nref,1,32,192,192)
    const void* refIdx = d_in[3];
    const void* curInd = d_in[4];
    int nref = in_sizes[0] / (CF * NPIX);

    float* ws  = (float*)d_ws;
    float* ftT = ws;
    float* frT = ftT + (size_t)NPIX * CF;
    float* qrT = frT + (size_t)nref * NPIX * CF;
    float* corr = qrT + (size_t)nref * NPIX * CQ;

    int total = NPIX * CF + nref * NPIX * CF + nref * NPIX * CQ;
    prep_kernel<<<(total + 255) / 256, 256, 0, stream>>>(fr, ft, q, nref, ftT, frT, qrT);
    corr_band<<<dim3(HW * 9, nref), 256, 0, stream>>>(ftT, frT, refIdx, curInd, corr);
    corr_fuse<<<dim3(NPIX), 64 * nref, 0, stream>>>(ftT, frT, qrT, corr, refIdx, curInd,
                                                    nref, (float*)d_out);
}

// Round 9
// 118.871 us; speedup vs baseline: 1.5887x; 1.1751x over previous
//
#include <hip/hip_runtime.h>
#include <math.h>

#define HW 48
#define NPIX 2304          // 48*48
#define CF 64
#define CQ 32
#define RAD 12
#define PP 25
#define NTAP 625           // 25*25
#define KTOP 20
#define DILINT 16
#define QW 192
#define CSTRIDE 640        // corr row stride (625 padded)
#define NPB 6              // pixels per corr_band block
#define NC 30              // staged columns per row (j+dx: 0..29)
#define LROW 68            // LDS col stride in floats
#define DGS 28             // dgrid row stride

// ---- helpers ---------------------------------------------------------------

// ref_index may arrive as int32 or int64; detect via first 8 bytes.
__device__ inline int read_ref_index(const void* rip, int r) {
    const long long* p64 = (const long long*)rip;
    long long v0 = p64[0];
    if (v0 >= 0 && v0 < 1000000) return (int)p64[r];   // plausible int64 layout
    return ((const int*)rip)[r];                       // int32 layout
}

__device__ inline int get_dil(const void* refIdx, const void* curInd, int r,
                              bool* isLong) {
    int cur = ((const int*)curInd)[0];
    int gap = cur - read_ref_index(refIdx, r);
    *isLong = gap > DILINT;
    return *isLong ? min(4, gap / DILINT + 1) : 1;
}

// ---- kernel 1: layout prep -------------------------------------------------
__global__ void prep_kernel(const float* __restrict__ fr,
                            const float* __restrict__ ft,
                            const float* __restrict__ q, int nref,
                            float* __restrict__ ftT,
                            float* __restrict__ frT,
                            float* __restrict__ qrT) {
    int i = blockIdx.x * blockDim.x + threadIdx.x;
    int tft = NPIX * CF;
    int tfr = nref * NPIX * CF;
    int tqr = nref * NPIX * CQ;
    if (i < tft) {
        int p = i >> 6, c = i & 63;
        ftT[i] = ft[c * NPIX + p];
    } else if (i < tft + tfr) {
        int j = i - tft;
        int rr = j / (NPIX * CF);
        int rem = j % (NPIX * CF);
        int p = rem >> 6, c = rem & 63;
        frT[j] = fr[((size_t)rr * CF + c) * NPIX + p];
    } else if (i < tft + tfr + tqr) {
        int j = i - tft - tfr;
        int rr = j / (NPIX * CQ);
        int rem = j % (NPIX * CQ);
        int p = rem >> 5, c = rem & 31;
        int y = p / HW, x = p % HW;
        qrT[j] = q[(((size_t)rr * CQ + c) * QW + 4 * y) * QW + 4 * x];
    }
}

// ---- kernel 2a: integer-tap correlation, row-staged (unchanged) ------------
__global__ __launch_bounds__(256) void corr_band(
    const float* __restrict__ ftT, const float* __restrict__ frT,
    const void* __restrict__ refIdx, const void* __restrict__ curInd,
    float* __restrict__ corr) {
    __shared__ float lrow[NC * LROW];

    int tid = threadIdx.x;
    int bx = blockIdx.x % 9;
    int y = blockIdx.x / 9;
    int r = blockIdx.y;

    bool isLong;
    int dil = get_dil(refIdx, curInd, r, &isLong);
    int nb = (dil == 3) ? 9 : 8;
    if (bx >= nb) return;

    int m = bx % dil, grp = bx / dil;
    int npr = HW / dil;

    int T = tid;
    bool active = T < NPB * PP;
    int j = active ? T / PP : 0;
    int dxi = active ? T - PP * j : 0;
    int xoff = grp * NPB + j;
    bool pvalid = active && (xoff < npr);
    int xj = m + dil * xoff;
    int pj = pvalid ? (y * HW + xj) : 0;
    int lc = j + dxi;

    float4 fq[16];
    const float4* fp = (const float4*)(ftT + (size_t)pj * CF);
#pragma unroll
    for (int i = 0; i < 16; ++i) fq[i] = fp[i];

    const float* frb = frT + (size_t)r * NPIX * CF;
    float* outb = corr + ((size_t)r * NPIX + pj) * CSTRIDE + dxi;
    int gc0 = m + dil * (grp * NPB - RAD);

    for (int dy = 0; dy < PP; ++dy) {
        int yy = y + dil * (dy - RAD);
        if (yy < 0 || yy >= HW) {
            if (pvalid) outb[dy * PP] = 0.f;
            continue;
        }
        for (int k = tid; k < NC * 16; k += 256) {
            int col = k >> 4, sub = k & 15;
            int gc = gc0 + dil * col;
            float4 v = {0.f, 0.f, 0.f, 0.f};
            if (gc >= 0 && gc < HW)
                v = *(const float4*)(frb + ((size_t)yy * HW + gc) * CF + sub * 4);
            *(float4*)(lrow + col * LROW + sub * 4) = v;
        }
        __syncthreads();
        if (pvalid) {
            const float* bp = lrow + lc * LROW;
            float s = 0.f;
#pragma unroll
            for (int i = 0; i < 16; ++i) {
                float4 b = *(const float4*)(bp + 4 * i);
                s += fq[i].x * b.x + fq[i].y * b.y + fq[i].z * b.z + fq[i].w * b.w;
            }
            outb[dy * PP] = s;
        }
        __syncthreads();
    }
}

// ---- kernel 2b: fused per-pixel block, one wave per ref --------------------
// Phase A: wave w loads creg for ref w; long wave computes softmax offsets.
// Phase B: ALL waves cooperate on each long ref's 26x26 corner grid.
// Phase C: long wave blends; every wave does topK; fused finalize.
__global__ __launch_bounds__(192) void corr_fuse(
    const float* __restrict__ ftT, const float* __restrict__ frT,
    const float* __restrict__ qrT, const float* __restrict__ corr,
    const void* __restrict__ refIdx, const void* __restrict__ curInd,
    int nref, float* __restrict__ out) {
    __shared__ float dgw_s[3][27 * DGS];
    __shared__ float valsL[96];
    __shared__ int   topiL[96];
    __shared__ float accL[3][64];
    __shared__ float ssmL[3][64];
    __shared__ float offL[3][2];

    int tid = threadIdx.x;
    int wid = tid >> 6, lane = tid & 63;
    int p = blockIdx.x;
    int y = p / HW, x = p % HW;
    int r = wid;                      // one wave per ref (block = 64*nref)

    bool isLong;
    int dil = get_dil(refIdx, curInd, r, &isLong);
    float oy = 0.f, ox = 0.f;

    const float* cb = corr + ((size_t)r * NPIX + p) * CSTRIDE;
    float creg[10];
#pragma unroll
    for (int jj = 0; jj < 10; ++jj) {
        int t = lane + 64 * jj;
        creg[jj] = (t < NTAP) ? cb[t] : -INFINITY;
    }

    if (isLong) {
        // softmax over 625 taps -> expected offsets
        float M = -INFINITY;
#pragma unroll
        for (int jj = 0; jj < 10; ++jj) M = fmaxf(M, creg[jj]);
#pragma unroll
        for (int s = 32; s; s >>= 1) M = fmaxf(M, __shfl_xor(M, s, 64));
        float s0 = 0.f, sy = 0.f, sx = 0.f;
#pragma unroll
        for (int jj = 0; jj < 10; ++jj) {
            int t = lane + 64 * jj;
            if (t < NTAP) {
                float e = expf(creg[jj] - M);
                int dy = t / PP - RAD, dx = t % PP - RAD;
                s0 += e; sy += e * (float)dy; sx += e * (float)dx;
            }
        }
#pragma unroll
        for (int s = 32; s; s >>= 1) {
            s0 += __shfl_xor(s0, s, 64);
            sy += __shfl_xor(sy, s, 64);
            sx += __shfl_xor(sx, s, 64);
        }
        oy = sy / s0 * (float)dil;
        ox = sx / s0 * (float)dil;
        if (lane == 0) { offL[r][0] = oy; offL[r][1] = ox; }
    }
    __syncthreads();

    // Phase B: cooperative corner grids (all threads, each long ref)
    for (int rr = 0; rr < nref; ++rr) {
        bool rrLong;
        get_dil(refIdx, curInd, rr, &rrLong);
        if (!rrLong) continue;                  // block-uniform
        float roy = offL[rr][0], rox = offL[rr][1];
        float fy = (float)y + roy, fx = (float)x + rox;
        int iy0 = (int)floorf(fy), ix0 = (int)floorf(fx);

        int cs = tid & 15;
        int g2 = tid >> 4;                      // 0..11 coop-16 groups
        float4 fqc = ((const float4*)(ftT + (size_t)p * CF))[cs];
        const float* frb = frT + (size_t)rr * NPIX * CF;
        float* dgw = dgw_s[rr];
        int colbase = ix0 - RAD;
        for (int a = 0; a < 26; ++a) {
            int yy = iy0 - RAD + a;
            bool yok = (yy >= 0 && yy < HW);
            const float* rowp = frb + (size_t)(yok ? yy : 0) * (HW * CF);
#pragma unroll
            for (int i = 0; i < 3; ++i) {
                int lc2 = 12 * i + g2;          // 0..35, use <26
                int xx2 = colbase + lc2;
                int xs = min(max(xx2, 0), HW - 1);
                float s = 0.f;
                if (yok && lc2 < 26) {
                    float4 b = *(const float4*)(rowp + xs * CF + 4 * cs);
                    s = fqc.x * b.x + fqc.y * b.y + fqc.z * b.z + fqc.w * b.w;
                    s = (xx2 >= 0 && xx2 < HW) ? s : 0.f;
                }
                s += __shfl_xor(s, 1, 64);
                s += __shfl_xor(s, 2, 64);
                s += __shfl_xor(s, 4, 64);
                s += __shfl_xor(s, 8, 64);
                if (cs == 0 && lc2 < 26) dgw[a * DGS + lc2] = s;
            }
        }
    }
    __syncthreads();

    // Phase C: long wave blends its creg from the corner grid
    if (isLong) {
        float fy = (float)y + oy, fx = (float)x + ox;
        float fy0 = floorf(fy), fx0 = floorf(fx);
        float wy = fy - fy0, wx = fx - fx0;
        const float* dgw = dgw_s[r];
        float w00 = (1.f - wy) * (1.f - wx), w01 = (1.f - wy) * wx;
        float w10 = wy * (1.f - wx), w11 = wy * wx;
#pragma unroll
        for (int jj = 0; jj < 10; ++jj) {
            int t = lane + 64 * jj;
            if (t < NTAP) {
                int a = t / PP, bcol = t % PP;
                creg[jj] = w00 * dgw[a * DGS + bcol] + w01 * dgw[a * DGS + bcol + 1] +
                           w10 * dgw[(a + 1) * DGS + bcol] + w11 * dgw[(a + 1) * DGS + bcol + 1];
            }
        }
    }

    // top-K for this wave's ref: tie -> lowest tap index
    for (int k = 0; k < KTOP; ++k) {
        float bv = creg[0]; int bt = lane;
#pragma unroll
        for (int jj = 1; jj < 10; ++jj) {
            int t = lane + 64 * jj;
            if (creg[jj] > bv) { bv = creg[jj]; bt = t; }
        }
#pragma unroll
        for (int s = 32; s; s >>= 1) {
            float ov = __shfl_xor(bv, s, 64);
            int ot = __shfl_xor(bt, s, 64);
            if (ov > bv || (ov == bv && ot < bt)) { bv = ov; bt = ot; }
        }
        if (lane == 0) { valsL[r * KTOP + k] = bv; topiL[r * KTOP + k] = bt; }
        if ((bt & 63) == lane) {
            int jj2 = bt >> 6;
#pragma unroll
            for (int jj = 0; jj < 10; ++jj)
                if (jj == jj2) creg[jj] = -INFINITY;
        }
    }
    __syncthreads();

    // per-wave partial finalize: own ref's 20 taps; lane = (channel, half)
    int c = lane & 31, h = lane >> 5;
    int nk = nref * KTOP;
    float m = -INFINITY;
    for (int k = 0; k < nk; ++k) m = fmaxf(m, valsL[k]);

    float ssum = 0.f, acc = 0.f;
    const float* qb = qrT + (size_t)r * NPIX * CQ;
    for (int k2 = 0; k2 < KTOP / 2; ++k2) {
        int k = r * KTOP + h * (KTOP / 2) + k2;
        float e = expf(valsL[k] - m);
        ssum += e;
        int id = topiL[k];
        int dr = id / PP - RAD, dc = id % PP - RAD;
        float img = 0.f;
        if (isLong) {
            float py = (float)y + oy + (float)dr;
            float px = (float)x + ox + (float)dc;
            float fy0 = floorf(py), fx0 = floorf(px);
            int y0 = (int)fy0, x0 = (int)fx0;
            float wy = py - fy0, wx = px - fx0;
            float w00 = (1.f - wy) * (1.f - wx), w01 = (1.f - wy) * wx;
            float w10 = wy * (1.f - wx), w11 = wy * wx;
            if (y0 >= 0 && y0 < HW && x0 >= 0 && x0 < HW)
                img += w00 * qb[(y0 * HW + x0) * CQ + c];
            if (y0 >= 0 && y0 < HW && x0 + 1 >= 0 && x0 + 1 < HW)
                img += w01 * qb[(y0 * HW + x0 + 1) * CQ + c];
            if (y0 + 1 >= 0 && y0 + 1 < HW && x0 >= 0 && x0 < HW)
                img += w10 * qb[((y0 + 1) * HW + x0) * CQ + c];
            if (y0 + 1 >= 0 && y0 + 1 < HW && x0 + 1 >= 0 && x0 + 1 < HW)
                img += w11 * qb[((y0 + 1) * HW + x0 + 1) * CQ + c];
        } else {
            int yy = y + dr, xx = x + dc;
            if (yy >= 0 && yy < HW && xx >= 0 && xx < HW)
                img = qb[(yy * HW + xx) * CQ + c];
        }
        acc += e * img;
    }
    accL[wid][lane] = acc;
    ssmL[wid][lane] = ssum;
    __syncthreads();

    if (wid == 0) {
        float ta = 0.f, ts = 0.f;
        for (int w = 0; w < nref; ++w) { ta += accL[w][lane]; ts += ssmL[w][lane]; }
        ta += __shfl_xor(ta, 32, 64);
        ts += __shfl_xor(ts, 32, 64);
        if (h == 0) out[(size_t)c * NPIX + p] = ta / ts;
    }
}

// ---- launcher --------------------------------------------------------------
extern "C" void kernel_launch(void* const* d_in, const int* in_sizes, int n_in,
                              void* d_out, int out_size, void* d_ws, size_t ws_size,
                              hipStream_t stream) {
    const float* fr = (const float*)d_in[0];   // (nref,1,64,48,48)
    const float* ft = (const float*)d_in[1];   // (1,64,48,48)
    const float* q  = (const float*)d_in[2];   // (nref,1,32,192,192)
    const void* refIdx = d_in[3];
    const void* curInd = d_in[4];
    int nref = in_sizes[0] / (CF * NPIX);

    float* ws  = (float*)d_ws;
    float* ftT = ws;
    float* frT = ftT + (size_t)NPIX * CF;
    float* qrT = frT + (size_t)nref * NPIX * CF;
    float* corr = qrT + (size_t)nref * NPIX * CQ;

    int total = NPIX * CF + nref * NPIX * CF + nref * NPIX * CQ;
    prep_kernel<<<(total + 255) / 256, 256, 0, stream>>>(fr, ft, q, nref, ftT, frT, qrT);
    corr_band<<<dim3(HW * 9, nref), 256, 0, stream>>>(ftT, frT, refIdx, curInd, corr);
    corr_fuse<<<dim3(NPIX), 64 * nref, 0, stream>>>(ftT, frT, qrT, corr, refIdx, curInd,
                                                    nref, (float*)d_out);
}